// Round 1
// baseline (508.325 us; speedup 1.0000x reference)
//
#include <hip/hip_runtime.h>

// ---------------------------------------------------------------------------
// GQA block: out = Attn(x@Wq^T, x@Wk^T, x@Wv^T; sliding-window+sink) @ Wo^T
// B=2 T=2048 C=2048, NH=16 NKV=4 HS=128, WINDOW=1024 SINK=4.
// All matmuls in bf16 MFMA (16x16x32), accumulate fp32. fp32 in/out per ref.
// ---------------------------------------------------------------------------

#define T_SEQ 2048
#define NH    16
#define NKV   4
#define HS    128
#define CDIM  2048
#define WIN   1024
#define SINKN 4

typedef __bf16 bf16x8 __attribute__((ext_vector_type(8)));
typedef float  f32x4  __attribute__((ext_vector_type(4)));

#define MFMA16(A, B, C) __builtin_amdgcn_mfma_f32_16x16x32_bf16(A, B, C, 0, 0, 0)

__device__ inline unsigned short f2bu(float f) {  // fp32 -> bf16 bits, RNE
  unsigned int u = __float_as_uint(f);
  u += 0x7fffu + ((u >> 16) & 1u);
  return (unsigned short)(u >> 16);
}
__device__ inline __bf16 us2b(unsigned short u) {
  union { unsigned short u; __bf16 b; } t; t.u = u; return t.b;
}
__device__ inline f32x4 fzero4() { f32x4 z = {0.f, 0.f, 0.f, 0.f}; return z; }

// ---------------- fp32 -> bf16 conversion (vectorized x4) ------------------
__global__ __launch_bounds__(256) void f2b_kernel(const float* __restrict__ in,
                                                  unsigned short* __restrict__ out,
                                                  int n) {
  int i = (blockIdx.x * 256 + threadIdx.x) * 4;
  if (i >= n) return;
  float4 v = *reinterpret_cast<const float4*>(in + i);
  ushort4 o;
  o.x = f2bu(v.x); o.y = f2bu(v.y); o.z = f2bu(v.z); o.w = f2bu(v.w);
  *reinterpret_cast<ushort4*>(out + i) = o;
}

// ---------------- C = A (M,K) @ B^T (N,K), bf16 in, OutT out ----------------
// 128x128 tile, BK=32, 4 waves each 64x64 (4x4 MFMA 16x16x32 tiles).
// LDS rows padded to 40 elems (stride 80B) -> 2-way banks only (free, m136).
__device__ inline void storeC(unsigned short* p, float v) { *p = f2bu(v); }
__device__ inline void storeC(float* p, float v) { *p = v; }

template <typename OutT>
__global__ __launch_bounds__(256) void gemm_abt(const unsigned short* __restrict__ A,
                                                const unsigned short* __restrict__ B,
                                                OutT* __restrict__ C,
                                                int M, int N, int K) {
  __shared__ __align__(16) unsigned short As[128 * 40];
  __shared__ __align__(16) unsigned short Bs[128 * 40];
  const int tid  = threadIdx.x;
  const int wave = tid >> 6, lane = tid & 63;
  const int quad = lane >> 4, l16 = lane & 15;
  const int wm = (wave >> 1) * 64, wn = (wave & 1) * 64;
  const int tm = blockIdx.x * 128, tn = blockIdx.y * 128;

  f32x4 acc[4][4];
#pragma unroll
  for (int i = 0; i < 4; ++i)
#pragma unroll
    for (int j = 0; j < 4; ++j) acc[i][j] = fzero4();

  for (int k0 = 0; k0 < K; k0 += 32) {
    __syncthreads();  // protect previous iteration's LDS reads
#pragma unroll
    for (int it = 0; it < 2; ++it) {
      int f = (it * 256 + tid) * 8;   // elem idx in 128x32 tile
      int r = f >> 5, c = f & 31;
      *reinterpret_cast<float4*>(&As[r * 40 + c]) =
          *reinterpret_cast<const float4*>(&A[(size_t)(tm + r) * K + k0 + c]);
      *reinterpret_cast<float4*>(&Bs[r * 40 + c]) =
          *reinterpret_cast<const float4*>(&B[(size_t)(tn + r) * K + k0 + c]);
    }
    __syncthreads();
    bf16x8 af[4], bfr[4];
#pragma unroll
    for (int i = 0; i < 4; ++i) {
      af[i]  = *reinterpret_cast<const bf16x8*>(&As[(wm + i * 16 + l16) * 40 + quad * 8]);
      bfr[i] = *reinterpret_cast<const bf16x8*>(&Bs[(wn + i * 16 + l16) * 40 + quad * 8]);
    }
#pragma unroll
    for (int i = 0; i < 4; ++i)
#pragma unroll
      for (int j = 0; j < 4; ++j) acc[i][j] = MFMA16(af[i], bfr[j], acc[i][j]);
  }
  // epilogue: D row = quad*4+r, col = l16 (verified C/D layout m89/m91)
#pragma unroll
  for (int i = 0; i < 4; ++i)
#pragma unroll
    for (int j = 0; j < 4; ++j)
#pragma unroll
      for (int r = 0; r < 4; ++r) {
        int row = tm + wm + i * 16 + quad * 4 + r;
        int col = tn + wn + j * 16 + l16;
        storeC(&C[(size_t)row * N + col], acc[i][j][r]);
      }
}

// ---------------- flash attention, sliding window + sink --------------------
// grid (T/64, NH, B); block 256 = 4 waves; wave w owns queries qt0+16w..+15.
// K/V chunk of 32 keys staged in LDS (row stride 136 = pad), P via LDS
// round-trip (C-layout -> A-layout, m120-verified transform).
__global__ __launch_bounds__(256) void attn_kernel(const unsigned short* __restrict__ Q,
                                                   const unsigned short* __restrict__ Kg,
                                                   const unsigned short* __restrict__ Vg,
                                                   unsigned short* __restrict__ Y) {
  __shared__ __align__(16) unsigned short Ks[32 * 136];
  __shared__ __align__(16) unsigned short Vs[32 * 136];
  __shared__ __align__(16) unsigned short Ps[4 * 16 * 40];
  const int tid  = threadIdx.x;
  const int wave = tid >> 6, lane = tid & 63;
  const int quad = lane >> 4, l16 = lane & 15;
  const int qt0 = blockIdx.x * 64;
  const int h   = blockIdx.y;
  const int b   = blockIdx.z;
  const int kvh = h >> 2;
  const int bT  = b * T_SEQ;
  const int qb  = qt0 + wave * 16;
  const float scale = 0.08838834764831845f;  // 1/sqrt(128)

  // Q fragments (A-operand: m=l16, k=quad*8+j), 4 chunks of 32 dims
  bf16x8 qa[4];
  {
    const size_t qrow = (size_t)(bT + qb + l16) * CDIM + (size_t)h * HS;
#pragma unroll
    for (int c = 0; c < 4; ++c)
      qa[c] = *reinterpret_cast<const bf16x8*>(&Q[qrow + c * 32 + quad * 8]);
  }

  f32x4 o[8];
#pragma unroll
  for (int nt = 0; nt < 8; ++nt) o[nt] = fzero4();
  float m_r[4] = {-1e30f, -1e30f, -1e30f, -1e30f};
  float l_r[4] = {0.f, 0.f, 0.f, 0.f};

  int start32 = (qt0 > 1023) ? ((qt0 - 1023) & ~31) : 0;
  int has_sink = (start32 > 0) ? 1 : 0;
  int nchunks = ((qt0 + 64 - start32) >> 5) + has_sink;
  unsigned short* Pw = &Ps[wave * 640];

  for (int ci = 0; ci < nchunks; ++ci) {
    int kt = (has_sink && ci == 0) ? 0 : start32 + (ci - has_sink) * 32;
    __syncthreads();  // prior chunk's K/V reads done
    // stage 32 keys x 128 dims of K and V
#pragma unroll
    for (int it = 0; it < 2; ++it) {
      int f = (it * 256 + tid) * 8;
      int key = f >> 7, dim = f & 127;
      size_t grow = (size_t)(bT + kt + key) * (NKV * HS) + (size_t)kvh * HS + dim;
      *reinterpret_cast<float4*>(&Ks[key * 136 + dim]) =
          *reinterpret_cast<const float4*>(&Kg[grow]);
      *reinterpret_cast<float4*>(&Vs[key * 136 + dim]) =
          *reinterpret_cast<const float4*>(&Vg[grow]);
    }
    __syncthreads();

    // S = Q K^T for 32 keys (two 16-key n-tiles)
    f32x4 s0 = fzero4(), s1 = fzero4();
#pragma unroll
    for (int c = 0; c < 4; ++c) {
      bf16x8 kf0 = *reinterpret_cast<const bf16x8*>(&Ks[l16 * 136 + c * 32 + quad * 8]);
      bf16x8 kf1 = *reinterpret_cast<const bf16x8*>(&Ks[(l16 + 16) * 136 + c * 32 + quad * 8]);
      s0 = MFMA16(qa[c], kf0, s0);
      s1 = MFMA16(qa[c], kf1, s1);
    }

    // mask + online softmax; S element (row=quad*4+r, col=l16)
    int kj0 = kt + l16, kj1 = kt + 16 + l16;
#pragma unroll
    for (int r = 0; r < 4; ++r) {
      int qi = qb + quad * 4 + r;
      bool ok0 = ((kj0 <= qi) && (kj0 + (WIN - 1) >= qi)) || ((kj0 < SINKN) && (qi >= SINKN));
      bool ok1 = ((kj1 <= qi) && (kj1 + (WIN - 1) >= qi)) || ((kj1 < SINKN) && (qi >= SINKN));
      float v0 = ok0 ? s0[r] * scale : -1e30f;
      float v1 = ok1 ? s1[r] * scale : -1e30f;
      float mx = fmaxf(v0, v1);
      mx = fmaxf(mx, __shfl_xor(mx, 1));
      mx = fmaxf(mx, __shfl_xor(mx, 2));
      mx = fmaxf(mx, __shfl_xor(mx, 4));
      mx = fmaxf(mx, __shfl_xor(mx, 8));
      float mnew  = fmaxf(m_r[r], mx);
      float alpha = __expf(m_r[r] - mnew);
      float p0 = __expf(v0 - mnew);
      float p1 = __expf(v1 - mnew);
      float rs = p0 + p1;
      rs += __shfl_xor(rs, 1);
      rs += __shfl_xor(rs, 2);
      rs += __shfl_xor(rs, 4);
      rs += __shfl_xor(rs, 8);
      l_r[r] = l_r[r] * alpha + rs;
      m_r[r] = mnew;
#pragma unroll
      for (int nt = 0; nt < 8; ++nt) o[nt][r] *= alpha;
      // P to LDS in (query,key) layout for A-operand reload
      Pw[(quad * 4 + r) * 40 + l16]      = f2bu(p0);
      Pw[(quad * 4 + r) * 40 + 16 + l16] = f2bu(p1);
    }
    asm volatile("s_waitcnt lgkmcnt(0)" ::: "memory");  // wave-local P visibility

    // O += P V  (P: A-operand m=l16,k=quad*8+j; V: B-operand scalar gathers)
    bf16x8 pf = *reinterpret_cast<const bf16x8*>(&Pw[l16 * 40 + quad * 8]);
#pragma unroll
    for (int nt = 0; nt < 8; ++nt) {
      bf16x8 vf;
#pragma unroll
      for (int j = 0; j < 8; ++j)
        vf[j] = us2b(Vs[(quad * 8 + j) * 136 + nt * 16 + l16]);
      o[nt] = MFMA16(pf, vf, o[nt]);
    }
  }

  float inv[4];
#pragma unroll
  for (int r = 0; r < 4; ++r) inv[r] = 1.f / l_r[r];
#pragma unroll
  for (int nt = 0; nt < 8; ++nt)
#pragma unroll
    for (int r = 0; r < 4; ++r) {
      int q = qb + quad * 4 + r;
      Y[(size_t)(bT + q) * CDIM + (size_t)h * HS + nt * 16 + l16] =
          f2bu(o[nt][r] * inv[r]);
    }
}

// ---------------------------------------------------------------------------
extern "C" void kernel_launch(void* const* d_in, const int* in_sizes, int n_in,
                              void* d_out, int out_size, void* d_ws, size_t ws_size,
                              hipStream_t stream) {
  const float* x  = (const float*)d_in[0];
  const float* Wq = (const float*)d_in[1];
  const float* Wk = (const float*)d_in[2];
  const float* Wv = (const float*)d_in[3];
  const float* Wo = (const float*)d_in[4];
  float* out = (float*)d_out;

  // workspace layout (bf16 elems); total 62.9 MB
  unsigned short* base = (unsigned short*)d_ws;
  unsigned short* xb  = base;             // x bf16        (8388608)
  unsigned short* wqb = xb  + 8388608;    // Wq bf16       (4194304)
  unsigned short* wkb = wqb + 4194304;    // Wk bf16       (1048576)
  unsigned short* wvb = wkb + 1048576;    // Wv bf16       (1048576)
  unsigned short* wob = wvb + 1048576;    // Wo bf16       (4194304)
  unsigned short* Qb  = wob + 4194304;    // Q             (8388608)
  unsigned short* Kb  = Qb  + 8388608;    // K             (2097152)
  unsigned short* Vb  = Kb  + 2097152;    // V             (2097152)
  unsigned short* Yb  = xb;               // y aliases xb (x dead after QKV)

  f2b_kernel<<<8192, 256, 0, stream>>>(x,  xb,  8388608);
  f2b_kernel<<<4096, 256, 0, stream>>>(Wq, wqb, 4194304);
  f2b_kernel<<<1024, 256, 0, stream>>>(Wk, wkb, 1048576);
  f2b_kernel<<<1024, 256, 0, stream>>>(Wv, wvb, 1048576);
  f2b_kernel<<<4096, 256, 0, stream>>>(Wo, wob, 4194304);

  gemm_abt<unsigned short><<<dim3(32, 16), 256, 0, stream>>>(xb, wqb, Qb, 4096, 2048, 2048);
  gemm_abt<unsigned short><<<dim3(32, 4),  256, 0, stream>>>(xb, wkb, Kb, 4096, 512,  2048);
  gemm_abt<unsigned short><<<dim3(32, 4),  256, 0, stream>>>(xb, wvb, Vb, 4096, 512,  2048);

  attn_kernel<<<dim3(32, 16, 2), 256, 0, stream>>>(Qb, Kb, Vb, Yb);

  gemm_abt<float><<<dim3(32, 16), 256, 0, stream>>>(Yb, wob, out, 4096, 2048, 2048);
}